// Round 1
// baseline (4953.067 us; speedup 1.0000x reference)
//
#include <hip/hip_runtime.h>
#include <hip/hip_bf16.h>

#define NN 40000
#define EE 640000
#define ET 680000   // EE + NN self loops
#define HID 256

__device__ __forceinline__ unsigned enc_f32(float f){
    unsigned u = __float_as_uint(f);
    return (u & 0x80000000u) ? ~u : (u | 0x80000000u);
}
__device__ __forceinline__ float dec_f32(unsigned u){
    unsigned v = (u & 0x80000000u) ? (u & 0x7FFFFFFFu) : ~u;
    return __uint_as_float(v);
}

// ---------------- GEMM: C[M,Nc] = A[M,K] @ B[K,Nc], f32, tiles 64x64x16 ----------------
__global__ __launch_bounds__(256) void gemm_f32(
    const float* __restrict__ A, const float* __restrict__ B, float* __restrict__ C,
    int M, int Nc, int K)
{
    __shared__ float As[16][65];
    __shared__ float Bs[16][65];
    int tid = threadIdx.x;
    int tx = tid & 15, ty = tid >> 4;
    int rb = blockIdx.x * 64, cb = blockIdx.y * 64;
    float acc[4][4] = {};
    for (int kb = 0; kb < K; kb += 16) {
        #pragma unroll
        for (int i = 0; i < 4; i++) {
            int idx = tid + i * 256;
            int r = idx >> 4, kk = idx & 15;
            As[kk][r] = A[(size_t)(rb + r) * K + kb + kk];
        }
        #pragma unroll
        for (int i = 0; i < 4; i++) {
            int idx = tid + i * 256;
            int kk = idx >> 6, c = idx & 63;
            Bs[kk][c] = B[(size_t)(kb + kk) * Nc + cb + c];
        }
        __syncthreads();
        #pragma unroll
        for (int kk = 0; kk < 16; kk++) {
            float a[4], b[4];
            #pragma unroll
            for (int i = 0; i < 4; i++) a[i] = As[kk][ty * 4 + i];
            #pragma unroll
            for (int j = 0; j < 4; j++) b[j] = Bs[kk][tx * 4 + j];
            #pragma unroll
            for (int i = 0; i < 4; i++)
                #pragma unroll
                for (int j = 0; j < 4; j++) acc[i][j] += a[i] * b[j];
        }
        __syncthreads();
    }
    #pragma unroll
    for (int i = 0; i < 4; i++) {
        int r = rb + ty * 4 + i;
        #pragma unroll
        for (int j = 0; j < 4; j++)
            C[(size_t)r * Nc + cb + tx * 4 + j] = acc[i][j];
    }
}

// GEMM (skip proj) fused with BN + ELU epilogue, in-place on H (= out0 buffer):
// H[r][c] = elu((H[r][c]-mu_c)*rsqrt(var_c+eps)*gamma_c + beta_c) + (x@W_skip)[r][c] + b_skip[c]
__global__ __launch_bounds__(256) void gemm_skip_bn(
    const float* __restrict__ A, const float* __restrict__ B, float* __restrict__ H,
    const float* __restrict__ gamma, const float* __restrict__ beta,
    const float* __restrict__ bnsum, const float* __restrict__ bnsq,
    const float* __restrict__ bskip, int M, int Nc, int K)
{
    __shared__ float As[16][65];
    __shared__ float Bs[16][65];
    int tid = threadIdx.x;
    int tx = tid & 15, ty = tid >> 4;
    int rb = blockIdx.x * 64, cb = blockIdx.y * 64;
    float acc[4][4] = {};
    for (int kb = 0; kb < K; kb += 16) {
        #pragma unroll
        for (int i = 0; i < 4; i++) {
            int idx = tid + i * 256;
            int r = idx >> 4, kk = idx & 15;
            As[kk][r] = A[(size_t)(rb + r) * K + kb + kk];
        }
        #pragma unroll
        for (int i = 0; i < 4; i++) {
            int idx = tid + i * 256;
            int kk = idx >> 6, c = idx & 63;
            Bs[kk][c] = B[(size_t)(kb + kk) * Nc + cb + c];
        }
        __syncthreads();
        #pragma unroll
        for (int kk = 0; kk < 16; kk++) {
            float a[4], b[4];
            #pragma unroll
            for (int i = 0; i < 4; i++) a[i] = As[kk][ty * 4 + i];
            #pragma unroll
            for (int j = 0; j < 4; j++) b[j] = Bs[kk][tx * 4 + j];
            #pragma unroll
            for (int i = 0; i < 4; i++)
                #pragma unroll
                for (int j = 0; j < 4; j++) acc[i][j] += a[i] * b[j];
        }
        __syncthreads();
    }
    const float invN = 1.0f / (float)M;
    #pragma unroll
    for (int j = 0; j < 4; j++) {
        int c = cb + tx * 4 + j;
        float mu = bnsum[c] * invN;
        float var = bnsq[c] * invN - mu * mu;
        float inv = rsqrtf(var + 1e-5f) * gamma[c];
        float bet = beta[c];
        float bsk = bskip[c];
        #pragma unroll
        for (int i = 0; i < 4; i++) {
            int r = rb + ty * 4 + i;
            size_t o = (size_t)r * Nc + c;
            float v = H[o];
            float bn = (v - mu) * inv + bet;
            float el = bn > 0.f ? bn : (expf(bn) - 1.f);
            H[o] = el + acc[i][j] + bsk;
        }
    }
}

// ---------------- per-node attention logits, layer 0 (8 heads x 32) ----------------
__global__ __launch_bounds__(256) void attn_node0(
    const float* __restrict__ xp, const float* __restrict__ att_s,
    const float* __restrict__ att_d, float* __restrict__ a_s, float* __restrict__ a_d)
{
    int t = blockIdx.x * blockDim.x + threadIdx.x;
    if (t >= NN * 8) return;
    int n = t >> 3, h = t & 7;
    const float4* xr = (const float4*)(xp + (size_t)n * 256 + h * 32);
    const float4* as4 = (const float4*)(att_s + h * 32);
    const float4* ad4 = (const float4*)(att_d + h * 32);
    float s = 0.f, dd = 0.f;
    #pragma unroll
    for (int i = 0; i < 8; i++) {
        float4 v = xr[i], a = as4[i], b = ad4[i];
        s  += v.x * a.x + v.y * a.y + v.z * a.z + v.w * a.w;
        dd += v.x * b.x + v.y * b.y + v.z * b.z + v.w * b.w;
    }
    a_s[t] = s; a_d[t] = dd;
}

// ---------------- per-node attention logits, layer 1 (1 head x 256), wave per node ----
__global__ __launch_bounds__(256) void attn_node1(
    const float* __restrict__ xp, const float* __restrict__ att_s,
    const float* __restrict__ att_d, float* __restrict__ a_s, float* __restrict__ a_d)
{
    int w = (blockIdx.x * 256 + threadIdx.x) >> 6;
    int lane = threadIdx.x & 63;
    if (w >= NN) return;
    float4 v = ((const float4*)(xp + (size_t)w * 256))[lane];
    float4 a = ((const float4*)att_s)[lane];
    float4 b = ((const float4*)att_d)[lane];
    float s  = v.x * a.x + v.y * a.y + v.z * a.z + v.w * a.w;
    float dd = v.x * b.x + v.y * b.y + v.z * b.z + v.w * b.w;
    #pragma unroll
    for (int off = 32; off; off >>= 1) {
        s  += __shfl_down(s, off);
        dd += __shfl_down(dd, off);
    }
    if (lane == 0) { a_s[w] = s; a_d[w] = dd; }
}

// ---------------- edge kernels, layer 0 ----------------
__global__ __launch_bounds__(256) void edge_logits0(
    const int* __restrict__ ei, const float* __restrict__ a_s, const float* __restrict__ a_d,
    float* __restrict__ ebuf, unsigned* __restrict__ menc)
{
    int t = blockIdx.x * blockDim.x + threadIdx.x;
    if (t >= ET * 8) return;
    int e = t >> 3, h = t & 7;
    int s, d;
    if (e < EE) { s = ei[e]; d = ei[EE + e]; } else { s = d = e - EE; }
    float v = a_s[s * 8 + h] + a_d[d * 8 + h];
    v = v > 0.f ? v : 0.2f * v;
    ebuf[t] = v;
    atomicMax(&menc[d * 8 + h], enc_f32(v));
}

__global__ __launch_bounds__(256) void edge_exp0(
    const int* __restrict__ ei, float* __restrict__ ebuf,
    const unsigned* __restrict__ menc, float* __restrict__ denom)
{
    int t = blockIdx.x * blockDim.x + threadIdx.x;
    if (t >= ET * 8) return;
    int e = t >> 3, h = t & 7;
    int d;
    if (e < EE) { d = ei[EE + e]; } else { d = e - EE; }
    float m = dec_f32(menc[d * 8 + h]);
    float ex = expf(ebuf[t] - m);
    ebuf[t] = ex;
    atomicAdd(&denom[d * 8 + h], ex);
}

// wave per edge: out0[dst] += xp[src] * alpha  (256 cols, 4 per lane)
__global__ __launch_bounds__(256) void scatter0(
    const int* __restrict__ ei, const float* __restrict__ xp,
    const float* __restrict__ ebuf, const float* __restrict__ denom,
    float* __restrict__ out0)
{
    int w = (blockIdx.x * 256 + threadIdx.x) >> 6;
    int lane = threadIdx.x & 63;
    if (w >= ET) return;
    int s, d;
    if (w < EE) { s = ei[w]; d = ei[EE + w]; } else { s = d = w - EE; }
    int h = lane >> 3;
    float alpha = ebuf[(size_t)w * 8 + h] / (denom[d * 8 + h] + 1e-16f);
    float4 v = ((const float4*)(xp + (size_t)s * 256))[lane];
    float* o = out0 + (size_t)d * 256 + lane * 4;
    atomicAdd(o + 0, v.x * alpha);
    atomicAdd(o + 1, v.y * alpha);
    atomicAdd(o + 2, v.z * alpha);
    atomicAdd(o + 3, v.w * alpha);
}

// ---------------- BN column stats ----------------
__global__ __launch_bounds__(256) void bn_stats(
    const float* __restrict__ H, float* __restrict__ bnsum, float* __restrict__ bnsq)
{
    int c = threadIdx.x;
    int r0 = blockIdx.x * 64;
    float s = 0.f, sq = 0.f;
    for (int r = r0; r < r0 + 64; r++) {
        float v = H[(size_t)r * 256 + c];
        s += v; sq += v * v;
    }
    atomicAdd(&bnsum[c], s);
    atomicAdd(&bnsq[c], sq);
}

// ---------------- edge kernels, layer 1 (1 head) ----------------
__global__ __launch_bounds__(256) void edge_logits1(
    const int* __restrict__ ei, const float* __restrict__ a_s, const float* __restrict__ a_d,
    float* __restrict__ ebuf, unsigned* __restrict__ menc)
{
    int e = blockIdx.x * blockDim.x + threadIdx.x;
    if (e >= ET) return;
    int s, d;
    if (e < EE) { s = ei[e]; d = ei[EE + e]; } else { s = d = e - EE; }
    float v = a_s[s] + a_d[d];
    v = v > 0.f ? v : 0.2f * v;
    ebuf[e] = v;
    atomicMax(&menc[d], enc_f32(v));
}

__global__ __launch_bounds__(256) void edge_exp1(
    const int* __restrict__ ei, float* __restrict__ ebuf,
    const unsigned* __restrict__ menc, float* __restrict__ denom)
{
    int e = blockIdx.x * blockDim.x + threadIdx.x;
    if (e >= ET) return;
    int d;
    if (e < EE) { d = ei[EE + e]; } else { d = e - EE; }
    float m = dec_f32(menc[d]);
    float ex = expf(ebuf[e] - m);
    ebuf[e] = ex;
    atomicAdd(&denom[d], ex);
}

__global__ __launch_bounds__(256) void init_out_b1(
    float* __restrict__ out, const float* __restrict__ b1)
{
    out[(size_t)blockIdx.x * 256 + threadIdx.x] = b1[threadIdx.x];
}

__global__ __launch_bounds__(256) void scatter1(
    const int* __restrict__ ei, const float* __restrict__ xp,
    const float* __restrict__ ebuf, const float* __restrict__ denom,
    float* __restrict__ out)
{
    int w = (blockIdx.x * 256 + threadIdx.x) >> 6;
    int lane = threadIdx.x & 63;
    if (w >= ET) return;
    int s, d;
    if (w < EE) { s = ei[w]; d = ei[EE + w]; } else { s = d = w - EE; }
    float alpha = ebuf[w] / (denom[d] + 1e-16f);
    float4 v = ((const float4*)(xp + (size_t)s * 256))[lane];
    float* o = out + (size_t)d * 256 + lane * 4;
    atomicAdd(o + 0, v.x * alpha);
    atomicAdd(o + 1, v.y * alpha);
    atomicAdd(o + 2, v.z * alpha);
    atomicAdd(o + 3, v.w * alpha);
}

extern "C" void kernel_launch(void* const* d_in, const int* in_sizes, int n_in,
                              void* d_out, int out_size, void* d_ws, size_t ws_size,
                              hipStream_t stream)
{
    const float* x      = (const float*)d_in[0];
    const int*   ei     = (const int*)d_in[1];
    const float* W0     = (const float*)d_in[2];
    const float* att_s0 = (const float*)d_in[3];
    const float* att_d0 = (const float*)d_in[4];
    // b0 (d_in[5]) cancels under BatchNorm -> unused
    const float* gamma0 = (const float*)d_in[6];
    const float* beta0  = (const float*)d_in[7];
    const float* W_skip = (const float*)d_in[8];
    const float* b_skip = (const float*)d_in[9];
    const float* W1     = (const float*)d_in[10];
    const float* att_s1 = (const float*)d_in[11];
    const float* att_d1 = (const float*)d_in[12];
    const float* b1     = (const float*)d_in[13];
    float* out = (float*)d_out;

    // workspace layout (floats)
    float* ws = (float*)d_ws;
    float* xp    = ws;                       // NN*256   (xp0, then xp1)
    float* out0  = xp + (size_t)NN * 256;    // NN*256   (conv0 accum -> h in place)
    float* ebuf  = out0 + (size_t)NN * 256;  // ET*8     (e0; first ET reused for e1)
    float* a_s   = ebuf + (size_t)ET * 8;    // NN*8
    float* a_d   = a_s + (size_t)NN * 8;     // NN*8
    unsigned* menc = (unsigned*)(a_d + (size_t)NN * 8); // NN*8
    float* denom = (float*)(menc + (size_t)NN * 8);     // NN*8
    float* bnsum = denom + (size_t)NN * 8;   // 256
    float* bnsq  = bnsum + 256;              // 256

    // ---- layer 0 ----
    hipMemsetAsync(out0, 0, (size_t)NN * 256 * 4, stream);
    hipMemsetAsync(menc, 0, (size_t)NN * 8 * 4, stream);
    hipMemsetAsync(denom, 0, (size_t)NN * 8 * 4, stream);
    hipMemsetAsync(bnsum, 0, 512 * 4, stream);

    dim3 gemm_grid(NN / 64, 256 / 64);
    gemm_f32<<<gemm_grid, 256, 0, stream>>>(x, W0, xp, NN, 256, 128);
    attn_node0<<<(NN * 8 + 255) / 256, 256, 0, stream>>>(xp, att_s0, att_d0, a_s, a_d);
    edge_logits0<<<(ET * 8 + 255) / 256, 256, 0, stream>>>(ei, a_s, a_d, ebuf, menc);
    edge_exp0<<<(ET * 8 + 255) / 256, 256, 0, stream>>>(ei, ebuf, menc, denom);
    scatter0<<<ET / 4, 256, 0, stream>>>(ei, xp, ebuf, denom, out0);

    // ---- BN + ELU + skip (fused into skip GEMM epilogue, in-place on out0) ----
    bn_stats<<<NN / 64, 256, 0, stream>>>(out0, bnsum, bnsq);
    gemm_skip_bn<<<gemm_grid, 256, 0, stream>>>(x, W_skip, out0, gamma0, beta0,
                                                bnsum, bnsq, b_skip, NN, 256, 128);

    // ---- layer 1 ----
    gemm_f32<<<gemm_grid, 256, 0, stream>>>(out0, W1, xp, NN, 256, 256);
    attn_node1<<<(NN * 64 + 255) / 256, 256, 0, stream>>>(xp, att_s1, att_d1, a_s, a_d);
    hipMemsetAsync(menc, 0, (size_t)NN * 4, stream);
    hipMemsetAsync(denom, 0, (size_t)NN * 4, stream);
    edge_logits1<<<(ET + 255) / 256, 256, 0, stream>>>(ei, a_s, a_d, ebuf, menc);
    edge_exp1<<<(ET + 255) / 256, 256, 0, stream>>>(ei, ebuf, menc, denom);
    init_out_b1<<<NN, 256, 0, stream>>>(out, b1);
    scatter1<<<ET / 4, 256, 0, stream>>>(ei, xp, ebuf, denom, out);
}

// Round 2
// 633.757 us; speedup vs baseline: 7.8154x; 7.8154x over previous
//
#include <hip/hip_runtime.h>
#include <hip/hip_bf16.h>

#define NN 40000
#define EE 640000
#define ET 680000   // EE + NN self loops
#define HID 256

// ---------------- GEMM: C[M,Nc] = A[M,K] @ B[K,Nc], f32, tiles 64x64x16 ----------------
__global__ __launch_bounds__(256) void gemm_f32(
    const float* __restrict__ A, const float* __restrict__ B, float* __restrict__ C,
    int M, int Nc, int K)
{
    __shared__ float As[16][65];
    __shared__ float Bs[16][65];
    int tid = threadIdx.x;
    int tx = tid & 15, ty = tid >> 4;
    int rb = blockIdx.x * 64, cb = blockIdx.y * 64;
    float acc[4][4] = {};
    for (int kb = 0; kb < K; kb += 16) {
        #pragma unroll
        for (int i = 0; i < 4; i++) {
            int idx = tid + i * 256;
            int r = idx >> 4, kk = idx & 15;
            As[kk][r] = A[(size_t)(rb + r) * K + kb + kk];
        }
        #pragma unroll
        for (int i = 0; i < 4; i++) {
            int idx = tid + i * 256;
            int kk = idx >> 6, c = idx & 63;
            Bs[kk][c] = B[(size_t)(kb + kk) * Nc + cb + c];
        }
        __syncthreads();
        #pragma unroll
        for (int kk = 0; kk < 16; kk++) {
            float a[4], b[4];
            #pragma unroll
            for (int i = 0; i < 4; i++) a[i] = As[kk][ty * 4 + i];
            #pragma unroll
            for (int j = 0; j < 4; j++) b[j] = Bs[kk][tx * 4 + j];
            #pragma unroll
            for (int i = 0; i < 4; i++)
                #pragma unroll
                for (int j = 0; j < 4; j++) acc[i][j] += a[i] * b[j];
        }
        __syncthreads();
    }
    #pragma unroll
    for (int i = 0; i < 4; i++) {
        int r = rb + ty * 4 + i;
        #pragma unroll
        for (int j = 0; j < 4; j++)
            C[(size_t)r * Nc + cb + tx * 4 + j] = acc[i][j];
    }
}

// GEMM (skip proj) fused with BN + ELU epilogue, in-place on H (= out0 buffer)
__global__ __launch_bounds__(256) void gemm_skip_bn(
    const float* __restrict__ A, const float* __restrict__ B, float* __restrict__ H,
    const float* __restrict__ gamma, const float* __restrict__ beta,
    const float* __restrict__ bnsum, const float* __restrict__ bnsq,
    const float* __restrict__ bskip, int M, int Nc, int K)
{
    __shared__ float As[16][65];
    __shared__ float Bs[16][65];
    int tid = threadIdx.x;
    int tx = tid & 15, ty = tid >> 4;
    int rb = blockIdx.x * 64, cb = blockIdx.y * 64;
    float acc[4][4] = {};
    for (int kb = 0; kb < K; kb += 16) {
        #pragma unroll
        for (int i = 0; i < 4; i++) {
            int idx = tid + i * 256;
            int r = idx >> 4, kk = idx & 15;
            As[kk][r] = A[(size_t)(rb + r) * K + kb + kk];
        }
        #pragma unroll
        for (int i = 0; i < 4; i++) {
            int idx = tid + i * 256;
            int kk = idx >> 6, c = idx & 63;
            Bs[kk][c] = B[(size_t)(kb + kk) * Nc + cb + c];
        }
        __syncthreads();
        #pragma unroll
        for (int kk = 0; kk < 16; kk++) {
            float a[4], b[4];
            #pragma unroll
            for (int i = 0; i < 4; i++) a[i] = As[kk][ty * 4 + i];
            #pragma unroll
            for (int j = 0; j < 4; j++) b[j] = Bs[kk][tx * 4 + j];
            #pragma unroll
            for (int i = 0; i < 4; i++)
                #pragma unroll
                for (int j = 0; j < 4; j++) acc[i][j] += a[i] * b[j];
        }
        __syncthreads();
    }
    const float invN = 1.0f / (float)M;
    #pragma unroll
    for (int j = 0; j < 4; j++) {
        int c = cb + tx * 4 + j;
        float mu = bnsum[c] * invN;
        float var = bnsq[c] * invN - mu * mu;
        float inv = rsqrtf(var + 1e-5f) * gamma[c];
        float bet = beta[c];
        float bsk = bskip[c];
        #pragma unroll
        for (int i = 0; i < 4; i++) {
            int r = rb + ty * 4 + i;
            size_t o = (size_t)r * Nc + c;
            float v = H[o];
            float bn = (v - mu) * inv + bet;
            float el = bn > 0.f ? bn : (expf(bn) - 1.f);
            H[o] = el + acc[i][j] + bsk;
        }
    }
}

// ---------------- CSR build (by dst), reused by both layers ----------------
__global__ __launch_bounds__(256) void csr_count(const int* __restrict__ ei, int* __restrict__ deg)
{
    int e = blockIdx.x * blockDim.x + threadIdx.x;
    if (e >= ET) return;
    int d = (e < EE) ? ei[EE + e] : (e - EE);
    atomicAdd(&deg[d], 1);
}

__global__ __launch_bounds__(1024) void exscan(
    const int* __restrict__ deg, int* __restrict__ rowptr, int* __restrict__ cursor)
{
    __shared__ int buf[1024];
    __shared__ int carry;
    int tid = threadIdx.x;
    if (tid == 0) carry = 0;
    __syncthreads();
    for (int base = 0; base < NN; base += 1024) {
        int i = base + tid;
        int v = (i < NN) ? deg[i] : 0;
        buf[tid] = v;
        __syncthreads();
        #pragma unroll
        for (int off = 1; off < 1024; off <<= 1) {
            int t = (tid >= off) ? buf[tid - off] : 0;
            __syncthreads();
            buf[tid] += t;
            __syncthreads();
        }
        int excl = buf[tid] - v + carry;
        if (i < NN) { rowptr[i] = excl; cursor[i] = excl; }
        __syncthreads();
        if (tid == 0) carry += buf[1023];
        __syncthreads();
    }
    if (tid == 0) rowptr[NN] = carry;
}

__global__ __launch_bounds__(256) void csr_fill(
    const int* __restrict__ ei, int* __restrict__ cursor, int* __restrict__ adj)
{
    int e = blockIdx.x * blockDim.x + threadIdx.x;
    if (e >= ET) return;
    int s, d;
    if (e < EE) { s = ei[e]; d = ei[EE + e]; } else { s = d = e - EE; }
    int pos = atomicAdd(&cursor[d], 1);
    adj[pos] = s;
}

// ---------------- per-node attention logits, layer 0 (8 heads x 32) ----------------
__global__ __launch_bounds__(256) void attn_node0(
    const float* __restrict__ xp, const float* __restrict__ att_s,
    const float* __restrict__ att_d, float* __restrict__ a_s, float* __restrict__ a_d)
{
    int t = blockIdx.x * blockDim.x + threadIdx.x;
    if (t >= NN * 8) return;
    int n = t >> 3, h = t & 7;
    const float4* xr = (const float4*)(xp + (size_t)n * 256 + h * 32);
    const float4* as4 = (const float4*)(att_s + h * 32);
    const float4* ad4 = (const float4*)(att_d + h * 32);
    float s = 0.f, dd = 0.f;
    #pragma unroll
    for (int i = 0; i < 8; i++) {
        float4 v = xr[i], a = as4[i], b = ad4[i];
        s  += v.x * a.x + v.y * a.y + v.z * a.z + v.w * a.w;
        dd += v.x * b.x + v.y * b.y + v.z * b.z + v.w * b.w;
    }
    a_s[t] = s; a_d[t] = dd;
}

// ---------------- per-node attention logits, layer 1 (1 head x 256) ----------------
__global__ __launch_bounds__(256) void attn_node1(
    const float* __restrict__ xp, const float* __restrict__ att_s,
    const float* __restrict__ att_d, float* __restrict__ a_s, float* __restrict__ a_d)
{
    int w = (blockIdx.x * 256 + threadIdx.x) >> 6;
    int lane = threadIdx.x & 63;
    if (w >= NN) return;
    float4 v = ((const float4*)(xp + (size_t)w * 256))[lane];
    float4 a = ((const float4*)att_s)[lane];
    float4 b = ((const float4*)att_d)[lane];
    float s  = v.x * a.x + v.y * a.y + v.z * a.z + v.w * a.w;
    float dd = v.x * b.x + v.y * b.y + v.z * b.z + v.w * b.w;
    #pragma unroll
    for (int off = 32; off; off >>= 1) {
        s  += __shfl_down(s, off);
        dd += __shfl_down(dd, off);
    }
    if (lane == 0) { a_s[w] = s; a_d[w] = dd; }
}

// ---------------- gather, layer 0: wave per dst node ----------------
// out0[d][c] = sum_e w_e * xp[src_e][c] / sum_e w_e,   w_e = exp(leaky(a_s[s][h]+a_d[d][h]))
__global__ __launch_bounds__(256) void gather0(
    const int* __restrict__ adj, const int* __restrict__ rowptr,
    const float* __restrict__ xp, const float* __restrict__ a_s,
    const float* __restrict__ a_d, float* __restrict__ out0)
{
    int w = (blockIdx.x * 256 + threadIdx.x) >> 6;
    int lane = threadIdx.x & 63;
    if (w >= NN) return;
    int h = lane >> 3;                      // 8 lanes per head, 4 channels per lane
    float ad = a_d[w * 8 + h];
    int beg = rowptr[w], end = rowptr[w + 1];
    float4 acc = {0.f, 0.f, 0.f, 0.f};
    float den = 0.f;
    for (int p = beg; p < end; p++) {
        int s = adj[p];
        float e = a_s[s * 8 + h] + ad;
        e = e > 0.f ? e : 0.2f * e;
        float wgt = expf(e);
        den += wgt;
        float4 v = ((const float4*)(xp + (size_t)s * 256))[lane];
        acc.x += wgt * v.x; acc.y += wgt * v.y;
        acc.z += wgt * v.z; acc.w += wgt * v.w;
    }
    float inv = 1.f / (den + 1e-16f);
    float4 r = {acc.x * inv, acc.y * inv, acc.z * inv, acc.w * inv};
    ((float4*)(out0 + (size_t)w * 256))[lane] = r;
}

// ---------------- gather, layer 1 (1 head), +b1 ----------------
__global__ __launch_bounds__(256) void gather1(
    const int* __restrict__ adj, const int* __restrict__ rowptr,
    const float* __restrict__ xp, const float* __restrict__ a_s,
    const float* __restrict__ a_d, const float* __restrict__ b1,
    float* __restrict__ out)
{
    int w = (blockIdx.x * 256 + threadIdx.x) >> 6;
    int lane = threadIdx.x & 63;
    if (w >= NN) return;
    float ad = a_d[w];
    int beg = rowptr[w], end = rowptr[w + 1];
    float4 acc = {0.f, 0.f, 0.f, 0.f};
    float den = 0.f;
    for (int p = beg; p < end; p++) {
        int s = adj[p];
        float e = a_s[s] + ad;
        e = e > 0.f ? e : 0.2f * e;
        float wgt = expf(e);
        den += wgt;
        float4 v = ((const float4*)(xp + (size_t)s * 256))[lane];
        acc.x += wgt * v.x; acc.y += wgt * v.y;
        acc.z += wgt * v.z; acc.w += wgt * v.w;
    }
    float inv = 1.f / (den + 1e-16f);
    float4 b = ((const float4*)b1)[lane];
    float4 r = {acc.x * inv + b.x, acc.y * inv + b.y,
                acc.z * inv + b.z, acc.w * inv + b.w};
    ((float4*)(out + (size_t)w * 256))[lane] = r;
}

// ---------------- BN column stats ----------------
__global__ __launch_bounds__(256) void bn_stats(
    const float* __restrict__ H, float* __restrict__ bnsum, float* __restrict__ bnsq)
{
    int c = threadIdx.x;
    int r0 = blockIdx.x * 64;
    float s = 0.f, sq = 0.f;
    for (int r = r0; r < r0 + 64; r++) {
        float v = H[(size_t)r * 256 + c];
        s += v; sq += v * v;
    }
    atomicAdd(&bnsum[c], s);
    atomicAdd(&bnsq[c], sq);
}

extern "C" void kernel_launch(void* const* d_in, const int* in_sizes, int n_in,
                              void* d_out, int out_size, void* d_ws, size_t ws_size,
                              hipStream_t stream)
{
    const float* x      = (const float*)d_in[0];
    const int*   ei     = (const int*)d_in[1];
    const float* W0     = (const float*)d_in[2];
    const float* att_s0 = (const float*)d_in[3];
    const float* att_d0 = (const float*)d_in[4];
    // b0 (d_in[5]) cancels under BatchNorm -> unused
    const float* gamma0 = (const float*)d_in[6];
    const float* beta0  = (const float*)d_in[7];
    const float* W_skip = (const float*)d_in[8];
    const float* b_skip = (const float*)d_in[9];
    const float* W1     = (const float*)d_in[10];
    const float* att_s1 = (const float*)d_in[11];
    const float* att_d1 = (const float*)d_in[12];
    const float* b1     = (const float*)d_in[13];
    float* out = (float*)d_out;

    // workspace layout
    float* ws = (float*)d_ws;
    float* xp    = ws;                        // NN*256
    float* out0  = xp + (size_t)NN * 256;     // NN*256
    float* a_s   = out0 + (size_t)NN * 256;   // NN*8
    float* a_d   = a_s + (size_t)NN * 8;      // NN*8
    float* bnsum = a_d + (size_t)NN * 8;      // 256
    float* bnsq  = bnsum + 256;               // 256
    int*   deg    = (int*)(bnsq + 256);       // NN
    int*   rowptr = deg + NN;                 // NN+1
    int*   cursor = rowptr + NN + 1;          // NN
    int*   adj    = cursor + NN;              // ET

    // ---- CSR build (shared by both layers) ----
    hipMemsetAsync(deg, 0, (size_t)NN * 4, stream);
    hipMemsetAsync(bnsum, 0, 512 * 4, stream);
    csr_count<<<(ET + 255) / 256, 256, 0, stream>>>(ei, deg);
    exscan<<<1, 1024, 0, stream>>>(deg, rowptr, cursor);
    csr_fill<<<(ET + 255) / 256, 256, 0, stream>>>(ei, cursor, adj);

    dim3 gemm_grid(NN / 64, 256 / 64);

    // ---- layer 0 ----
    gemm_f32<<<gemm_grid, 256, 0, stream>>>(x, W0, xp, NN, 256, 128);
    attn_node0<<<(NN * 8 + 255) / 256, 256, 0, stream>>>(xp, att_s0, att_d0, a_s, a_d);
    gather0<<<(NN * 64 + 255) / 256, 256, 0, stream>>>(adj, rowptr, xp, a_s, a_d, out0);

    // ---- BN + ELU + skip (fused into skip GEMM epilogue, in-place on out0) ----
    bn_stats<<<NN / 64, 256, 0, stream>>>(out0, bnsum, bnsq);
    gemm_skip_bn<<<gemm_grid, 256, 0, stream>>>(x, W_skip, out0, gamma0, beta0,
                                                bnsum, bnsq, b_skip, NN, 256, 128);

    // ---- layer 1 ----
    gemm_f32<<<gemm_grid, 256, 0, stream>>>(out0, W1, xp, NN, 256, 256);
    attn_node1<<<(NN * 64 + 255) / 256, 256, 0, stream>>>(xp, att_s1, att_d1, a_s, a_d);
    gather1<<<(NN * 64 + 255) / 256, 256, 0, stream>>>(adj, rowptr, xp, a_s, a_d, b1, out);
}

// Round 3
// 439.346 us; speedup vs baseline: 11.2737x; 1.4425x over previous
//
#include <hip/hip_runtime.h>
#include <hip/hip_bf16.h>

#define NN 40000
#define EE 640000
#define ET 680000   // EE + NN self loops
#define MPAD 40064  // 313 * 128

typedef __attribute__((ext_vector_type(8))) short short8;
typedef __attribute__((ext_vector_type(4))) float f32x4;

__device__ __forceinline__ float bf2f(unsigned u) {
    return __uint_as_float(u << 16);
}
__device__ __forceinline__ unsigned short f2bf(float f) {
    unsigned u = __float_as_uint(f);
    return (unsigned short)((u + 0x7FFFu + ((u >> 16) & 1u)) >> 16);
}

// ---------------- converts ----------------
__global__ __launch_bounds__(256) void conv_x(const float* __restrict__ x,
                                              unsigned short* __restrict__ xb)
{
    int i = blockIdx.x * 256 + threadIdx.x;          // one per 4 elems
    if (i >= MPAD * 128 / 4) return;
    int row = (i * 4) >> 7;
    ushort4 o;
    if (row < NN) {
        float4 v = ((const float4*)x)[i];
        o.x = f2bf(v.x); o.y = f2bf(v.y); o.z = f2bf(v.z); o.w = f2bf(v.w);
    } else { o.x = o.y = o.z = o.w = 0; }
    ((ushort4*)xb)[i] = o;
}

// W[K][256] f32 -> Wt[256][K] bf16
__global__ __launch_bounds__(256) void conv_wt(const float* __restrict__ W,
                                               unsigned short* __restrict__ Wt, int K)
{
    int i = blockIdx.x * 256 + threadIdx.x;
    if (i >= K * 256) return;
    int c = i / K, k = i - c * K;
    Wt[i] = f2bf(W[(size_t)k * 256 + c]);
}

// ---------------- MFMA GEMM: C[MPAD][256](bf16) = A[MPAD][K](bf16) @ Bt^T ----------------
// Bt is [256][K] bf16 (pre-transposed). Block 128x128, 4 waves 2x2, wave 64x64.
__global__ __launch_bounds__(256) void gemm_bf16(
    const unsigned short* __restrict__ A, const unsigned short* __restrict__ Bt,
    unsigned short* __restrict__ C, int K)
{
    __shared__ unsigned short As[128 * 64];
    int tid = threadIdx.x;
    int rb = blockIdx.x * 128, cb = blockIdx.y * 128;
    int lane = tid & 63, wid = tid >> 6;
    int wm = (wid >> 1) * 64, wn = (wid & 1) * 64;
    int lr = lane & 15, lk = lane >> 4;
    f32x4 acc[4][4] = {};
    for (int kb = 0; kb < K; kb += 64) {
        #pragma unroll
        for (int i = 0; i < 4; i++) {
            int flat = tid + i * 256;
            int r = flat >> 3, c8 = flat & 7;
            int4 v = *(const int4*)(A + (size_t)(rb + r) * K + kb + c8 * 8);
            *(int4*)(&As[r * 64 + ((c8 ^ (r & 7)) * 8)]) = v;
        }
        __syncthreads();
        #pragma unroll
        for (int kk = 0; kk < 2; kk++) {
            int kbase = kb + kk * 32 + lk * 8;
            short8 bfr[4], afr[4];
            #pragma unroll
            for (int n = 0; n < 4; n++)
                bfr[n] = *(const short8*)(Bt + (size_t)(cb + wn + n * 16 + lr) * K + kbase);
            #pragma unroll
            for (int m = 0; m < 4; m++) {
                int row = wm + m * 16 + lr;
                int kchunk = kk * 4 + lk;
                afr[m] = *(const short8*)(&As[row * 64 + ((kchunk ^ (row & 7)) * 8)]);
            }
            #pragma unroll
            for (int m = 0; m < 4; m++)
                #pragma unroll
                for (int n = 0; n < 4; n++)
                    acc[m][n] = __builtin_amdgcn_mfma_f32_16x16x32_bf16(afr[m], bfr[n], acc[m][n], 0, 0, 0);
        }
        __syncthreads();
    }
    #pragma unroll
    for (int m = 0; m < 4; m++)
        #pragma unroll
        for (int n = 0; n < 4; n++) {
            int col = cb + wn + n * 16 + lr;
            #pragma unroll
            for (int j = 0; j < 4; j++) {
                int row = rb + wm + m * 16 + lk * 4 + j;
                C[(size_t)row * 256 + col] = f2bf(acc[m][n][j]);
            }
        }
}

// Same GEMM (skip = x @ W_skip) + BN/ELU epilogue on H (f32), writes h (bf16).
__global__ __launch_bounds__(256) void gemm_skip_bn(
    const unsigned short* __restrict__ A, const unsigned short* __restrict__ Bt,
    const float* __restrict__ H, unsigned short* __restrict__ Hb,
    const float* __restrict__ gamma, const float* __restrict__ beta,
    const float* __restrict__ bnsum, const float* __restrict__ bnsq,
    const float* __restrict__ bskip, int K)
{
    __shared__ unsigned short As[128 * 64];
    int tid = threadIdx.x;
    int rb = blockIdx.x * 128, cb = blockIdx.y * 128;
    int lane = tid & 63, wid = tid >> 6;
    int wm = (wid >> 1) * 64, wn = (wid & 1) * 64;
    int lr = lane & 15, lk = lane >> 4;
    f32x4 acc[4][4] = {};
    for (int kb = 0; kb < K; kb += 64) {
        #pragma unroll
        for (int i = 0; i < 4; i++) {
            int flat = tid + i * 256;
            int r = flat >> 3, c8 = flat & 7;
            int4 v = *(const int4*)(A + (size_t)(rb + r) * K + kb + c8 * 8);
            *(int4*)(&As[r * 64 + ((c8 ^ (r & 7)) * 8)]) = v;
        }
        __syncthreads();
        #pragma unroll
        for (int kk = 0; kk < 2; kk++) {
            int kbase = kb + kk * 32 + lk * 8;
            short8 bfr[4], afr[4];
            #pragma unroll
            for (int n = 0; n < 4; n++)
                bfr[n] = *(const short8*)(Bt + (size_t)(cb + wn + n * 16 + lr) * K + kbase);
            #pragma unroll
            for (int m = 0; m < 4; m++) {
                int row = wm + m * 16 + lr;
                int kchunk = kk * 4 + lk;
                afr[m] = *(const short8*)(&As[row * 64 + ((kchunk ^ (row & 7)) * 8)]);
            }
            #pragma unroll
            for (int m = 0; m < 4; m++)
                #pragma unroll
                for (int n = 0; n < 4; n++)
                    acc[m][n] = __builtin_amdgcn_mfma_f32_16x16x32_bf16(afr[m], bfr[n], acc[m][n], 0, 0, 0);
        }
        __syncthreads();
    }
    const float invN = 1.0f / (float)NN;
    #pragma unroll
    for (int n = 0; n < 4; n++) {
        int col = cb + wn + n * 16 + lr;
        float mu = bnsum[col] * invN;
        float var = bnsq[col] * invN - mu * mu;
        float inv = rsqrtf(var + 1e-5f) * gamma[col];
        float bet = beta[col], bsk = bskip[col];
        #pragma unroll
        for (int m = 0; m < 4; m++)
            #pragma unroll
            for (int j = 0; j < 4; j++) {
                int row = rb + wm + m * 16 + lk * 4 + j;
                float v = H[(size_t)row * 256 + col];
                float bn = (v - mu) * inv + bet;
                float el = bn > 0.f ? bn : (expf(bn) - 1.f);
                Hb[(size_t)row * 256 + col] = f2bf(el + acc[m][n][j] + bsk);
            }
    }
}

// ---------------- CSR build (by dst) ----------------
__global__ __launch_bounds__(256) void csr_count(const int* __restrict__ ei, int* __restrict__ deg)
{
    int e = blockIdx.x * blockDim.x + threadIdx.x;
    if (e >= ET) return;
    int d = (e < EE) ? ei[EE + e] : (e - EE);
    atomicAdd(&deg[d], 1);
}

__global__ __launch_bounds__(1024) void exscan(
    const int* __restrict__ deg, int* __restrict__ rowptr, int* __restrict__ cursor)
{
    __shared__ int buf[1024];
    __shared__ int carry;
    int tid = threadIdx.x;
    if (tid == 0) carry = 0;
    __syncthreads();
    for (int base = 0; base < NN; base += 1024) {
        int i = base + tid;
        int v = (i < NN) ? deg[i] : 0;
        buf[tid] = v;
        __syncthreads();
        #pragma unroll
        for (int off = 1; off < 1024; off <<= 1) {
            int t = (tid >= off) ? buf[tid - off] : 0;
            __syncthreads();
            buf[tid] += t;
            __syncthreads();
        }
        int excl = buf[tid] - v + carry;
        if (i < NN) { rowptr[i] = excl; cursor[i] = excl; }
        __syncthreads();
        if (tid == 0) carry += buf[1023];
        __syncthreads();
    }
    if (tid == 0) rowptr[NN] = carry;
}

__global__ __launch_bounds__(256) void csr_fill(
    const int* __restrict__ ei, int* __restrict__ cursor, int* __restrict__ adj)
{
    int e = blockIdx.x * blockDim.x + threadIdx.x;
    if (e >= ET) return;
    int s, d;
    if (e < EE) { s = ei[e]; d = ei[EE + e]; } else { s = d = e - EE; }
    int pos = atomicAdd(&cursor[d], 1);
    adj[pos] = s;
}

// ---------------- attention logits ----------------
__global__ __launch_bounds__(256) void attn_node0(
    const unsigned short* __restrict__ xp, const float* __restrict__ att_s,
    const float* __restrict__ att_d, float* __restrict__ a_s, float* __restrict__ a_d)
{
    int t = blockIdx.x * 256 + threadIdx.x;
    if (t >= NN * 8) return;
    int n = t >> 3, h = t & 7;
    const unsigned short* p = xp + (size_t)n * 256 + h * 32;
    float s = 0.f, dd = 0.f;
    #pragma unroll
    for (int i0 = 0; i0 < 32; i0 += 8) {
        uint4 raw = *(const uint4*)(p + i0);
        unsigned vals[4] = {raw.x, raw.y, raw.z, raw.w};
        #pragma unroll
        for (int q = 0; q < 4; q++) {
            float lo = bf2f(vals[q] & 0xffffu), hi = bf2f(vals[q] >> 16);
            s  += lo * att_s[h * 32 + i0 + q * 2] + hi * att_s[h * 32 + i0 + q * 2 + 1];
            dd += lo * att_d[h * 32 + i0 + q * 2] + hi * att_d[h * 32 + i0 + q * 2 + 1];
        }
    }
    a_s[t] = s; a_d[t] = dd;
}

__global__ __launch_bounds__(256) void attn_node1(
    const unsigned short* __restrict__ xp, const float* __restrict__ att_s,
    const float* __restrict__ att_d, float* __restrict__ a_s, float* __restrict__ a_d)
{
    int w = (blockIdx.x * 256 + threadIdx.x) >> 6;
    int lane = threadIdx.x & 63;
    if (w >= NN) return;
    ushort4 raw = ((const ushort4*)(xp + (size_t)w * 256))[lane];
    float4 a = ((const float4*)att_s)[lane];
    float4 b = ((const float4*)att_d)[lane];
    float v0 = bf2f(raw.x), v1 = bf2f(raw.y), v2 = bf2f(raw.z), v3 = bf2f(raw.w);
    float s  = v0 * a.x + v1 * a.y + v2 * a.z + v3 * a.w;
    float dd = v0 * b.x + v1 * b.y + v2 * b.z + v3 * b.w;
    #pragma unroll
    for (int off = 32; off; off >>= 1) {
        s  += __shfl_down(s, off);
        dd += __shfl_down(dd, off);
    }
    if (lane == 0) { a_s[w] = s; a_d[w] = dd; }
}

// ---------------- gathers (wave per dst node) ----------------
__global__ __launch_bounds__(256) void gather0(
    const int* __restrict__ adj, const int* __restrict__ rowptr,
    const unsigned short* __restrict__ xp, const float* __restrict__ a_s,
    const float* __restrict__ a_d, float* __restrict__ out0)
{
    int w = (blockIdx.x * 256 + threadIdx.x) >> 6;
    int lane = threadIdx.x & 63;
    if (w >= NN) return;
    int h = lane >> 3;
    float ad = a_d[w * 8 + h];
    int beg = rowptr[w], end = rowptr[w + 1];
    float4 acc = {0.f, 0.f, 0.f, 0.f};
    float den = 0.f;
    for (int p = beg; p < end; p++) {
        int s = adj[p];
        float e = a_s[s * 8 + h] + ad;
        e = e > 0.f ? e : 0.2f * e;
        float wgt = expf(e);
        den += wgt;
        uint2 raw = *(const uint2*)(xp + (size_t)s * 256 + lane * 4);
        acc.x += wgt * bf2f(raw.x & 0xffffu);
        acc.y += wgt * bf2f(raw.x >> 16);
        acc.z += wgt * bf2f(raw.y & 0xffffu);
        acc.w += wgt * bf2f(raw.y >> 16);
    }
    float inv = 1.f / (den + 1e-16f);
    float4 r = {acc.x * inv, acc.y * inv, acc.z * inv, acc.w * inv};
    ((float4*)(out0 + (size_t)w * 256))[lane] = r;
}

__global__ __launch_bounds__(256) void gather1(
    const int* __restrict__ adj, const int* __restrict__ rowptr,
    const unsigned short* __restrict__ xp, const float* __restrict__ a_s,
    const float* __restrict__ a_d, const float* __restrict__ b1,
    float* __restrict__ out)
{
    int w = (blockIdx.x * 256 + threadIdx.x) >> 6;
    int lane = threadIdx.x & 63;
    if (w >= NN) return;
    float ad = a_d[w];
    int beg = rowptr[w], end = rowptr[w + 1];
    float4 acc = {0.f, 0.f, 0.f, 0.f};
    float den = 0.f;
    for (int p = beg; p < end; p++) {
        int s = adj[p];
        float e = a_s[s] + ad;
        e = e > 0.f ? e : 0.2f * e;
        float wgt = expf(e);
        den += wgt;
        uint2 raw = *(const uint2*)(xp + (size_t)s * 256 + lane * 4);
        acc.x += wgt * bf2f(raw.x & 0xffffu);
        acc.y += wgt * bf2f(raw.x >> 16);
        acc.z += wgt * bf2f(raw.y & 0xffffu);
        acc.w += wgt * bf2f(raw.y >> 16);
    }
    float inv = 1.f / (den + 1e-16f);
    float4 b = ((const float4*)b1)[lane];
    float4 r = {acc.x * inv + b.x, acc.y * inv + b.y,
                acc.z * inv + b.z, acc.w * inv + b.w};
    ((float4*)(out + (size_t)w * 256))[lane] = r;
}

// ---------------- BN column stats ----------------
__global__ __launch_bounds__(256) void bn_stats(
    const float* __restrict__ H, float* __restrict__ bnsum, float* __restrict__ bnsq)
{
    int c = threadIdx.x;
    int r0 = blockIdx.x * 64;
    float s = 0.f, sq = 0.f;
    for (int r = r0; r < r0 + 64; r++) {
        float v = H[(size_t)r * 256 + c];
        s += v; sq += v * v;
    }
    atomicAdd(&bnsum[c], s);
    atomicAdd(&bnsq[c], sq);
}

extern "C" void kernel_launch(void* const* d_in, const int* in_sizes, int n_in,
                              void* d_out, int out_size, void* d_ws, size_t ws_size,
                              hipStream_t stream)
{
    const float* x      = (const float*)d_in[0];
    const int*   ei     = (const int*)d_in[1];
    const float* W0     = (const float*)d_in[2];
    const float* att_s0 = (const float*)d_in[3];
    const float* att_d0 = (const float*)d_in[4];
    // b0 (d_in[5]) cancels under BatchNorm -> unused
    const float* gamma0 = (const float*)d_in[6];
    const float* beta0  = (const float*)d_in[7];
    const float* W_skip = (const float*)d_in[8];
    const float* b_skip = (const float*)d_in[9];
    const float* W1     = (const float*)d_in[10];
    const float* att_s1 = (const float*)d_in[11];
    const float* att_d1 = (const float*)d_in[12];
    const float* b1     = (const float*)d_in[13];
    float* out = (float*)d_out;

    // workspace layout
    char* p = (char*)d_ws;
    unsigned short* x_bf  = (unsigned short*)p; p += (size_t)MPAD * 128 * 2;
    unsigned short* xp_bf = (unsigned short*)p; p += (size_t)MPAD * 256 * 2;   // xp0 then xp1
    unsigned short* h_bf  = (unsigned short*)p; p += (size_t)MPAD * 256 * 2;
    unsigned short* W0t   = (unsigned short*)p; p += (size_t)256 * 128 * 2;
    unsigned short* Wst   = (unsigned short*)p; p += (size_t)256 * 128 * 2;
    unsigned short* W1t   = (unsigned short*)p; p += (size_t)256 * 256 * 2;
    float* out0  = (float*)p; p += (size_t)MPAD * 256 * 4;
    float* a_s   = (float*)p; p += (size_t)NN * 8 * 4;
    float* a_d   = (float*)p; p += (size_t)NN * 8 * 4;
    float* bnsum = (float*)p; p += 256 * 4;
    float* bnsq  = (float*)p; p += 256 * 4;
    int* deg    = (int*)p; p += (size_t)NN * 4;
    int* rowptr = (int*)p; p += (size_t)(NN + 1) * 4;
    int* cursor = (int*)p; p += (size_t)NN * 4;
    int* adj    = (int*)p; p += (size_t)ET * 4;

    hipMemsetAsync(deg, 0, (size_t)NN * 4, stream);
    hipMemsetAsync(bnsum, 0, 512 * 4, stream);

    // converts
    conv_x<<<(MPAD * 128 / 4 + 255) / 256, 256, 0, stream>>>(x, x_bf);
    conv_wt<<<(128 * 256 + 255) / 256, 256, 0, stream>>>(W0, W0t, 128);
    conv_wt<<<(128 * 256 + 255) / 256, 256, 0, stream>>>(W_skip, Wst, 128);
    conv_wt<<<(256 * 256 + 255) / 256, 256, 0, stream>>>(W1, W1t, 256);

    // CSR build
    csr_count<<<(ET + 255) / 256, 256, 0, stream>>>(ei, deg);
    exscan<<<1, 1024, 0, stream>>>(deg, rowptr, cursor);
    csr_fill<<<(ET + 255) / 256, 256, 0, stream>>>(ei, cursor, adj);

    dim3 gg(MPAD / 128, 2);

    // ---- layer 0 ----
    gemm_bf16<<<gg, 256, 0, stream>>>(x_bf, W0t, xp_bf, 128);
    attn_node0<<<(NN * 8 + 255) / 256, 256, 0, stream>>>(xp_bf, att_s0, att_d0, a_s, a_d);
    gather0<<<(NN * 64 + 255) / 256, 256, 0, stream>>>(adj, rowptr, xp_bf, a_s, a_d, out0);

    // ---- BN + ELU + skip ----
    bn_stats<<<NN / 64, 256, 0, stream>>>(out0, bnsum, bnsq);
    gemm_skip_bn<<<gg, 256, 0, stream>>>(x_bf, Wst, out0, h_bf, gamma0, beta0,
                                         bnsum, bnsq, b_skip, 128);

    // ---- layer 1 ----
    gemm_bf16<<<gg, 256, 0, stream>>>(h_bf, W1t, xp_bf, 256);
    attn_node1<<<(NN * 64 + 255) / 256, 256, 0, stream>>>(xp_bf, att_s1, att_d1, a_s, a_d);
    gather1<<<(NN * 64 + 255) / 256, 256, 0, stream>>>(adj, rowptr, xp_bf, a_s, a_d, b1, out);
}

// Round 4
// 342.654 us; speedup vs baseline: 14.4550x; 1.2822x over previous
//
#include <hip/hip_runtime.h>
#include <hip/hip_bf16.h>

#define NN 40000
#define EE 640000
#define ET 680000   // EE + NN self loops
#define MPAD 40064  // 313 * 128

typedef __attribute__((ext_vector_type(8))) short short8;
typedef __attribute__((ext_vector_type(4))) float f32x4;

__device__ __forceinline__ float bf2f(unsigned u) {
    return __uint_as_float(u << 16);
}
__device__ __forceinline__ unsigned short f2bf(float f) {
    unsigned u = __float_as_uint(f);
    return (unsigned short)((u + 0x7FFFu + ((u >> 16) & 1u)) >> 16);
}
// unpack a packed pair of bf16 (1 instr each)
__device__ __forceinline__ void unpack2(unsigned u, float& lo, float& hi) {
    lo = __uint_as_float(u << 16);
    hi = __uint_as_float(u & 0xffff0000u);
}

// ---------------- converts ----------------
__global__ __launch_bounds__(256) void conv_x(const float* __restrict__ x,
                                              unsigned short* __restrict__ xb)
{
    int i = blockIdx.x * 256 + threadIdx.x;          // one per 4 elems
    if (i >= MPAD * 128 / 4) return;
    int row = (i * 4) >> 7;
    ushort4 o;
    if (row < NN) {
        float4 v = ((const float4*)x)[i];
        o.x = f2bf(v.x); o.y = f2bf(v.y); o.z = f2bf(v.z); o.w = f2bf(v.w);
    } else { o.x = o.y = o.z = o.w = 0; }
    ((ushort4*)xb)[i] = o;
}

// W[K][256] f32 -> Wt[256][K] bf16
__global__ __launch_bounds__(256) void conv_wt(const float* __restrict__ W,
                                               unsigned short* __restrict__ Wt, int K)
{
    int i = blockIdx.x * 256 + threadIdx.x;
    if (i >= K * 256) return;
    int c = i / K, k = i - c * K;
    Wt[i] = f2bf(W[(size_t)k * 256 + c]);
}

// ---------------- MFMA GEMM: C[MPAD][256](bf16) = A[MPAD][K](bf16) @ Bt^T ----------------
__global__ __launch_bounds__(256) void gemm_bf16(
    const unsigned short* __restrict__ A, const unsigned short* __restrict__ Bt,
    unsigned short* __restrict__ C, int K)
{
    __shared__ unsigned short As[128 * 64];
    int tid = threadIdx.x;
    int rb = blockIdx.x * 128, cb = blockIdx.y * 128;
    int lane = tid & 63, wid = tid >> 6;
    int wm = (wid >> 1) * 64, wn = (wid & 1) * 64;
    int lr = lane & 15, lk = lane >> 4;
    f32x4 acc[4][4] = {};
    for (int kb = 0; kb < K; kb += 64) {
        #pragma unroll
        for (int i = 0; i < 4; i++) {
            int flat = tid + i * 256;
            int r = flat >> 3, c8 = flat & 7;
            int4 v = *(const int4*)(A + (size_t)(rb + r) * K + kb + c8 * 8);
            *(int4*)(&As[r * 64 + ((c8 ^ (r & 7)) * 8)]) = v;
        }
        __syncthreads();
        #pragma unroll
        for (int kk = 0; kk < 2; kk++) {
            int kbase = kb + kk * 32 + lk * 8;
            short8 bfr[4], afr[4];
            #pragma unroll
            for (int n = 0; n < 4; n++)
                bfr[n] = *(const short8*)(Bt + (size_t)(cb + wn + n * 16 + lr) * K + kbase);
            #pragma unroll
            for (int m = 0; m < 4; m++) {
                int row = wm + m * 16 + lr;
                int kchunk = kk * 4 + lk;
                afr[m] = *(const short8*)(&As[row * 64 + ((kchunk ^ (row & 7)) * 8)]);
            }
            #pragma unroll
            for (int m = 0; m < 4; m++)
                #pragma unroll
                for (int n = 0; n < 4; n++)
                    acc[m][n] = __builtin_amdgcn_mfma_f32_16x16x32_bf16(afr[m], bfr[n], acc[m][n], 0, 0, 0);
        }
        __syncthreads();
    }
    #pragma unroll
    for (int m = 0; m < 4; m++)
        #pragma unroll
        for (int n = 0; n < 4; n++) {
            int col = cb + wn + n * 16 + lr;
            #pragma unroll
            for (int j = 0; j < 4; j++) {
                int row = rb + wm + m * 16 + lk * 4 + j;
                C[(size_t)row * 256 + col] = f2bf(acc[m][n][j]);
            }
        }
}

// Skip GEMM + BN/ELU epilogue. H (pre-BN conv0 out) is bf16; writes h (bf16).
__global__ __launch_bounds__(256) void gemm_skip_bn(
    const unsigned short* __restrict__ A, const unsigned short* __restrict__ Bt,
    const unsigned short* __restrict__ H, unsigned short* __restrict__ Hb,
    const float* __restrict__ gamma, const float* __restrict__ beta,
    const float* __restrict__ bnsum, const float* __restrict__ bnsq,
    const float* __restrict__ bskip, int K)
{
    __shared__ unsigned short As[128 * 64];
    int tid = threadIdx.x;
    int rb = blockIdx.x * 128, cb = blockIdx.y * 128;
    int lane = tid & 63, wid = tid >> 6;
    int wm = (wid >> 1) * 64, wn = (wid & 1) * 64;
    int lr = lane & 15, lk = lane >> 4;
    f32x4 acc[4][4] = {};
    for (int kb = 0; kb < K; kb += 64) {
        #pragma unroll
        for (int i = 0; i < 4; i++) {
            int flat = tid + i * 256;
            int r = flat >> 3, c8 = flat & 7;
            int4 v = *(const int4*)(A + (size_t)(rb + r) * K + kb + c8 * 8);
            *(int4*)(&As[r * 64 + ((c8 ^ (r & 7)) * 8)]) = v;
        }
        __syncthreads();
        #pragma unroll
        for (int kk = 0; kk < 2; kk++) {
            int kbase = kb + kk * 32 + lk * 8;
            short8 bfr[4], afr[4];
            #pragma unroll
            for (int n = 0; n < 4; n++)
                bfr[n] = *(const short8*)(Bt + (size_t)(cb + wn + n * 16 + lr) * K + kbase);
            #pragma unroll
            for (int m = 0; m < 4; m++) {
                int row = wm + m * 16 + lr;
                int kchunk = kk * 4 + lk;
                afr[m] = *(const short8*)(&As[row * 64 + ((kchunk ^ (row & 7)) * 8)]);
            }
            #pragma unroll
            for (int m = 0; m < 4; m++)
                #pragma unroll
                for (int n = 0; n < 4; n++)
                    acc[m][n] = __builtin_amdgcn_mfma_f32_16x16x32_bf16(afr[m], bfr[n], acc[m][n], 0, 0, 0);
        }
        __syncthreads();
    }
    const float invN = 1.0f / (float)NN;
    #pragma unroll
    for (int n = 0; n < 4; n++) {
        int col = cb + wn + n * 16 + lr;
        float mu = bnsum[col] * invN;
        float var = bnsq[col] * invN - mu * mu;
        float inv = rsqrtf(var + 1e-5f) * gamma[col];
        float bet = beta[col], bsk = bskip[col];
        #pragma unroll
        for (int m = 0; m < 4; m++)
            #pragma unroll
            for (int j = 0; j < 4; j++) {
                int row = rb + wm + m * 16 + lk * 4 + j;
                float v = bf2f(H[(size_t)row * 256 + col]);
                float bn = (v - mu) * inv + bet;
                float el = bn > 0.f ? bn : (__expf(bn) - 1.f);
                Hb[(size_t)row * 256 + col] = f2bf(el + acc[m][n][j] + bsk);
            }
    }
}

// ---------------- CSR build (by dst) ----------------
__global__ __launch_bounds__(256) void csr_count(const int* __restrict__ ei, int* __restrict__ deg)
{
    int e = blockIdx.x * blockDim.x + threadIdx.x;
    if (e >= ET) return;
    int d = (e < EE) ? ei[EE + e] : (e - EE);
    atomicAdd(&deg[d], 1);
}

// single block, shfl-based scan (3 barriers per 1024-chunk)
__global__ __launch_bounds__(1024) void exscan(
    const int* __restrict__ deg, int* __restrict__ rowptr, int* __restrict__ cursor)
{
    __shared__ int wsum[16];
    __shared__ int carry_s;
    int tid = threadIdx.x, lane = tid & 63, wid = tid >> 6;
    if (tid == 0) carry_s = 0;
    __syncthreads();
    for (int base = 0; base < NN; base += 1024) {
        int i = base + tid;
        int v = (i < NN) ? deg[i] : 0;
        int sc = v;
        #pragma unroll
        for (int off = 1; off < 64; off <<= 1) {
            int t = __shfl_up(sc, off);
            if (lane >= off) sc += t;
        }
        if (lane == 63) wsum[wid] = sc;
        __syncthreads();
        if (wid == 0 && lane < 16) {
            int t = wsum[lane];
            #pragma unroll
            for (int off = 1; off < 16; off <<= 1) {
                int u = __shfl_up(t, off);
                if (lane >= off) t += u;
            }
            wsum[lane] = t;   // inclusive scan of wave sums
        }
        __syncthreads();
        int carry = carry_s;
        int wpre = wid ? wsum[wid - 1] : 0;
        int excl = carry + wpre + sc - v;
        if (i < NN) { rowptr[i] = excl; cursor[i] = excl; }
        __syncthreads();      // all wsum reads done before next chunk overwrites
        if (tid == 0) carry_s = carry + wsum[15];
    }
    if (tid == 0) rowptr[NN] = carry_s;
}

__global__ __launch_bounds__(256) void csr_fill(
    const int* __restrict__ ei, int* __restrict__ cursor, int* __restrict__ adj)
{
    int e = blockIdx.x * blockDim.x + threadIdx.x;
    if (e >= ET) return;
    int s, d;
    if (e < EE) { s = ei[e]; d = ei[EE + e]; } else { s = d = e - EE; }
    int pos = atomicAdd(&cursor[d], 1);
    adj[pos] = s;
}

// ---------------- attention logits ----------------
__global__ __launch_bounds__(256) void attn_node0(
    const unsigned short* __restrict__ xp, const float* __restrict__ att_s,
    const float* __restrict__ att_d, float* __restrict__ a_s, float* __restrict__ a_d)
{
    int t = blockIdx.x * 256 + threadIdx.x;
    if (t >= NN * 8) return;
    int n = t >> 3, h = t & 7;
    const unsigned short* p = xp + (size_t)n * 256 + h * 32;
    float s = 0.f, dd = 0.f;
    #pragma unroll
    for (int i0 = 0; i0 < 32; i0 += 8) {
        uint4 raw = *(const uint4*)(p + i0);
        unsigned vals[4] = {raw.x, raw.y, raw.z, raw.w};
        #pragma unroll
        for (int q = 0; q < 4; q++) {
            float lo, hi;
            unpack2(vals[q], lo, hi);
            s  += lo * att_s[h * 32 + i0 + q * 2] + hi * att_s[h * 32 + i0 + q * 2 + 1];
            dd += lo * att_d[h * 32 + i0 + q * 2] + hi * att_d[h * 32 + i0 + q * 2 + 1];
        }
    }
    a_s[t] = s; a_d[t] = dd;
}

__global__ __launch_bounds__(256) void attn_node1(
    const unsigned short* __restrict__ xp, const float* __restrict__ att_s,
    const float* __restrict__ att_d, float* __restrict__ a_s, float* __restrict__ a_d)
{
    int w = (blockIdx.x * 256 + threadIdx.x) >> 6;
    int lane = threadIdx.x & 63;
    if (w >= NN) return;
    ushort4 raw = ((const ushort4*)(xp + (size_t)w * 256))[lane];
    float4 a = ((const float4*)att_s)[lane];
    float4 b = ((const float4*)att_d)[lane];
    float v0 = bf2f(raw.x), v1 = bf2f(raw.y), v2 = bf2f(raw.z), v3 = bf2f(raw.w);
    float s  = v0 * a.x + v1 * a.y + v2 * a.z + v3 * a.w;
    float dd = v0 * b.x + v1 * b.y + v2 * b.z + v3 * b.w;
    #pragma unroll
    for (int off = 32; off; off >>= 1) {
        s  += __shfl_down(s, off);
        dd += __shfl_down(dd, off);
    }
    if (lane == 0) { a_s[w] = s; a_d[w] = dd; }
}

// ---------------- gathers (wave per dst node), unroll x2 ----------------
__global__ __launch_bounds__(256) void gather0(
    const int* __restrict__ adj, const int* __restrict__ rowptr,
    const unsigned short* __restrict__ xp, const float* __restrict__ a_s,
    const float* __restrict__ a_d, unsigned short* __restrict__ out0)
{
    int w = (blockIdx.x * 256 + threadIdx.x) >> 6;
    int lane = threadIdx.x & 63;
    if (w >= NN) return;
    int h = lane >> 3;
    float ad = a_d[w * 8 + h];
    int p = rowptr[w], end = rowptr[w + 1];
    unsigned loff = (unsigned)lane * 8u;
    float ax0=0,ay0=0,az0=0,aw0=0, ax1=0,ay1=0,az1=0,aw1=0;
    float den0 = 0.f, den1 = 0.f;
    for (; p + 2 <= end; p += 2) {
        int s0 = adj[p], s1 = adj[p + 1];
        float e0 = a_s[s0 * 8 + h] + ad;
        float e1 = a_s[s1 * 8 + h] + ad;
        e0 = fmaxf(e0, 0.2f * e0);
        e1 = fmaxf(e1, 0.2f * e1);
        float w0 = __expf(e0), w1 = __expf(e1);
        uint2 r0 = *(const uint2*)((const char*)xp + ((unsigned)s0 * 512u + loff));
        uint2 r1 = *(const uint2*)((const char*)xp + ((unsigned)s1 * 512u + loff));
        den0 += w0; den1 += w1;
        float lo, hi;
        unpack2(r0.x, lo, hi); ax0 += w0 * lo; ay0 += w0 * hi;
        unpack2(r0.y, lo, hi); az0 += w0 * lo; aw0 += w0 * hi;
        unpack2(r1.x, lo, hi); ax1 += w1 * lo; ay1 += w1 * hi;
        unpack2(r1.y, lo, hi); az1 += w1 * lo; aw1 += w1 * hi;
    }
    if (p < end) {
        int s0 = adj[p];
        float e0 = a_s[s0 * 8 + h] + ad;
        e0 = fmaxf(e0, 0.2f * e0);
        float w0 = __expf(e0);
        uint2 r0 = *(const uint2*)((const char*)xp + ((unsigned)s0 * 512u + loff));
        den0 += w0;
        float lo, hi;
        unpack2(r0.x, lo, hi); ax0 += w0 * lo; ay0 += w0 * hi;
        unpack2(r0.y, lo, hi); az0 += w0 * lo; aw0 += w0 * hi;
    }
    float inv = 1.f / (den0 + den1 + 1e-16f);
    ushort4 o;
    o.x = f2bf((ax0 + ax1) * inv); o.y = f2bf((ay0 + ay1) * inv);
    o.z = f2bf((az0 + az1) * inv); o.w = f2bf((aw0 + aw1) * inv);
    ((ushort4*)(out0 + (size_t)w * 256))[lane] = o;
}

__global__ __launch_bounds__(256) void gather1(
    const int* __restrict__ adj, const int* __restrict__ rowptr,
    const unsigned short* __restrict__ xp, const float* __restrict__ a_s,
    const float* __restrict__ a_d, const float* __restrict__ b1,
    float* __restrict__ out)
{
    int w = (blockIdx.x * 256 + threadIdx.x) >> 6;
    int lane = threadIdx.x & 63;
    if (w >= NN) return;
    float ad = a_d[w];
    int p = rowptr[w], end = rowptr[w + 1];
    unsigned loff = (unsigned)lane * 8u;
    float ax0=0,ay0=0,az0=0,aw0=0, ax1=0,ay1=0,az1=0,aw1=0;
    float den0 = 0.f, den1 = 0.f;
    for (; p + 2 <= end; p += 2) {
        int s0 = adj[p], s1 = adj[p + 1];
        float e0 = a_s[s0] + ad;
        float e1 = a_s[s1] + ad;
        e0 = fmaxf(e0, 0.2f * e0);
        e1 = fmaxf(e1, 0.2f * e1);
        float w0 = __expf(e0), w1 = __expf(e1);
        uint2 r0 = *(const uint2*)((const char*)xp + ((unsigned)s0 * 512u + loff));
        uint2 r1 = *(const uint2*)((const char*)xp + ((unsigned)s1 * 512u + loff));
        den0 += w0; den1 += w1;
        float lo, hi;
        unpack2(r0.x, lo, hi); ax0 += w0 * lo; ay0 += w0 * hi;
        unpack2(r0.y, lo, hi); az0 += w0 * lo; aw0 += w0 * hi;
        unpack2(r1.x, lo, hi); ax1 += w1 * lo; ay1 += w1 * hi;
        unpack2(r1.y, lo, hi); az1 += w1 * lo; aw1 += w1 * hi;
    }
    if (p < end) {
        int s0 = adj[p];
        float e0 = a_s[s0] + ad;
        e0 = fmaxf(e0, 0.2f * e0);
        float w0 = __expf(e0);
        uint2 r0 = *(const uint2*)((const char*)xp + ((unsigned)s0 * 512u + loff));
        den0 += w0;
        float lo, hi;
        unpack2(r0.x, lo, hi); ax0 += w0 * lo; ay0 += w0 * hi;
        unpack2(r0.y, lo, hi); az0 += w0 * lo; aw0 += w0 * hi;
    }
    float inv = 1.f / (den0 + den1 + 1e-16f);
    float4 b = ((const float4*)b1)[lane];
    float4 r = {(ax0 + ax1) * inv + b.x, (ay0 + ay1) * inv + b.y,
                (az0 + az1) * inv + b.z, (aw0 + aw1) * inv + b.w};
    ((float4*)(out + (size_t)w * 256))[lane] = r;
}

// ---------------- BN column stats (bf16 input) ----------------
__global__ __launch_bounds__(256) void bn_stats(
    const unsigned short* __restrict__ H, float* __restrict__ bnsum, float* __restrict__ bnsq)
{
    int c = threadIdx.x;
    int r0 = blockIdx.x * 64;
    float s = 0.f, sq = 0.f;
    for (int r = r0; r < r0 + 64; r++) {
        float v = bf2f(H[(size_t)r * 256 + c]);
        s += v; sq += v * v;
    }
    atomicAdd(&bnsum[c], s);
    atomicAdd(&bnsq[c], sq);
}

extern "C" void kernel_launch(void* const* d_in, const int* in_sizes, int n_in,
                              void* d_out, int out_size, void* d_ws, size_t ws_size,
                              hipStream_t stream)
{
    const float* x      = (const float*)d_in[0];
    const int*   ei     = (const int*)d_in[1];
    const float* W0     = (const float*)d_in[2];
    const float* att_s0 = (const float*)d_in[3];
    const float* att_d0 = (const float*)d_in[4];
    // b0 (d_in[5]) cancels under BatchNorm -> unused
    const float* gamma0 = (const float*)d_in[6];
    const float* beta0  = (const float*)d_in[7];
    const float* W_skip = (const float*)d_in[8];
    const float* b_skip = (const float*)d_in[9];
    const float* W1     = (const float*)d_in[10];
    const float* att_s1 = (const float*)d_in[11];
    const float* att_d1 = (const float*)d_in[12];
    const float* b1     = (const float*)d_in[13];
    float* out = (float*)d_out;

    // workspace layout
    char* p = (char*)d_ws;
    unsigned short* x_bf  = (unsigned short*)p; p += (size_t)MPAD * 128 * 2;
    unsigned short* xp_bf = (unsigned short*)p; p += (size_t)MPAD * 256 * 2;   // xp0 then xp1
    unsigned short* h_bf  = (unsigned short*)p; p += (size_t)MPAD * 256 * 2;
    unsigned short* out0b = (unsigned short*)p; p += (size_t)MPAD * 256 * 2;
    unsigned short* W0t   = (unsigned short*)p; p += (size_t)256 * 128 * 2;
    unsigned short* Wst   = (unsigned short*)p; p += (size_t)256 * 128 * 2;
    unsigned short* W1t   = (unsigned short*)p; p += (size_t)256 * 256 * 2;
    float* a_s   = (float*)p; p += (size_t)NN * 8 * 4;
    float* a_d   = (float*)p; p += (size_t)NN * 8 * 4;
    float* bnsum = (float*)p; p += 256 * 4;
    float* bnsq  = (float*)p; p += 256 * 4;
    int* deg    = (int*)p; p += (size_t)NN * 4;
    int* rowptr = (int*)p; p += (size_t)(NN + 1) * 4;
    int* cursor = (int*)p; p += (size_t)NN * 4;
    int* adj    = (int*)p; p += (size_t)ET * 4;

    hipMemsetAsync(deg, 0, (size_t)NN * 4, stream);
    hipMemsetAsync(bnsum, 0, 512 * 4, stream);
    // deterministic pad rows for out0b (never written by gather0)
    hipMemsetAsync(out0b + (size_t)NN * 256, 0, (size_t)(MPAD - NN) * 256 * 2, stream);

    // converts
    conv_x<<<(MPAD * 128 / 4 + 255) / 256, 256, 0, stream>>>(x, x_bf);
    conv_wt<<<(128 * 256 + 255) / 256, 256, 0, stream>>>(W0, W0t, 128);
    conv_wt<<<(128 * 256 + 255) / 256, 256, 0, stream>>>(W_skip, Wst, 128);
    conv_wt<<<(256 * 256 + 255) / 256, 256, 0, stream>>>(W1, W1t, 256);

    // CSR build
    csr_count<<<(ET + 255) / 256, 256, 0, stream>>>(ei, deg);
    exscan<<<1, 1024, 0, stream>>>(deg, rowptr, cursor);
    csr_fill<<<(ET + 255) / 256, 256, 0, stream>>>(ei, cursor, adj);

    dim3 gg(MPAD / 128, 2);

    // ---- layer 0 ----
    gemm_bf16<<<gg, 256, 0, stream>>>(x_bf, W0t, xp_bf, 128);
    attn_node0<<<(NN * 8 + 255) / 256, 256, 0, stream>>>(xp_bf, att_s0, att_d0, a_s, a_d);
    gather0<<<(NN * 64 + 255) / 256, 256, 0, stream>>>(adj, rowptr, xp_bf, a_s, a_d, out0b);

    // ---- BN + ELU + skip ----
    bn_stats<<<NN / 64, 256, 0, stream>>>(out0b, bnsum, bnsq);
    gemm_skip_bn<<<gg, 256, 0, stream>>>(x_bf, Wst, out0b, h_bf, gamma0, beta0,
                                         bnsum, bnsq, b_skip, 128);

    // ---- layer 1 ----
    gemm_bf16<<<gg, 256, 0, stream>>>(h_bf, W1t, xp_bf, 256);
    attn_node1<<<(NN * 64 + 255) / 256, 256, 0, stream>>>(xp_bf, att_s1, att_d1, a_s, a_d);
    gather1<<<(NN * 64 + 255) / 256, 256, 0, stream>>>(adj, rowptr, xp_bf, a_s, a_d, b1, out);
}